// Round 7
// baseline (15518.454 us; speedup 1.0000x reference)
//
#include <hip/hip_runtime.h>
#include <hip/hip_bf16.h>

#define B_ 32
#define T_ 2048
#define D_ 512
#define H_ 1024
#define G4_ 4096
#define NBLK 128   // recurrent blocks (1 block/CU, co-resident)
#define JPB 8      // h-columns per recurrent block (H_/NBLK)
#define FSTRIDE 16 // one flag per 64B line

typedef __attribute__((ext_vector_type(8))) short short8;
typedef __attribute__((ext_vector_type(4))) float f32x4;
typedef __attribute__((ext_vector_type(4))) int i32x4;

__device__ __forceinline__ float sigmoidf_(float x) { return 1.0f / (1.0f + __expf(-x)); }
__device__ __forceinline__ float tanhf_(float x) {
  float e = __expf(2.0f * x);
  return 1.0f - 2.0f / (e + 1.0f);
}
__device__ __forceinline__ float bf16bits_to_f(unsigned short u) {
  return __builtin_bit_cast(float, (unsigned int)u << 16);
}
__device__ __forceinline__ unsigned short f_to_bf16bits(float f) {
  __hip_bfloat16 h = __float2bfloat16(f);
  return __builtin_bit_cast(unsigned short, h);
}

// ---------------------------------------------------------------------------
// Precompute xg[row][col] = sum_k x[row][k] * W_ih[col][k]   (row = tloc*32+b)
// ---------------------------------------------------------------------------
__global__ __launch_bounds__(256) void xw_gemm(const float* __restrict__ x,
                                               const float* __restrict__ Wih,
                                               __hip_bfloat16* __restrict__ xg,
                                               int t0) {
  __shared__ __align__(16) __hip_bfloat16 As[128][40];
  __shared__ __align__(16) __hip_bfloat16 Bs[128][40];
  __shared__ __align__(16) __hip_bfloat16 Cs[128][132];

  const int tid = threadIdx.x;
  const int bx = blockIdx.x;           // N tile (0..31)
  const int by = blockIdx.y;           // M tile
  const int lane = tid & 63, wave = tid >> 6;
  const int wm = wave >> 1, wn = wave & 1;
  const int lr = lane & 15, kq = (lane >> 4) * 8;

  const int r  = tid >> 1, ks = (tid & 1) * 16;
  const int rowA = by * 128 + r;
  const int bb = rowA & 31, tg = t0 + (rowA >> 5);
  const float* aptr = x  + ((size_t)bb * T_ + tg) * D_ + ks;
  const float* bptr = Wih + (size_t)(bx * 128 + r) * D_ + ks;

  f32x4 acc[4][4];
#pragma unroll
  for (int i = 0; i < 4; ++i)
#pragma unroll
    for (int jj = 0; jj < 4; ++jj) acc[i][jj] = (f32x4){0.f, 0.f, 0.f, 0.f};

  for (int k0 = 0; k0 < D_; k0 += 32) {
    __hip_bfloat16 ta[16], tb[16];
#pragma unroll
    for (int q = 0; q < 4; ++q) {
      f32x4 va = ((const f32x4*)(aptr + k0))[q];
      f32x4 vb = ((const f32x4*)(bptr + k0))[q];
#pragma unroll
      for (int e = 0; e < 4; ++e) {
        ta[q * 4 + e] = __float2bfloat16(va[e]);
        tb[q * 4 + e] = __float2bfloat16(vb[e]);
      }
    }
    __syncthreads();  // protect previous iter's readers
    *(short8*)&As[r][ks]     = *(const short8*)&ta[0];
    *(short8*)&As[r][ks + 8] = *(const short8*)&ta[8];
    *(short8*)&Bs[r][ks]     = *(const short8*)&tb[0];
    *(short8*)&Bs[r][ks + 8] = *(const short8*)&tb[8];
    __syncthreads();

    short8 af[4], bf[4];
#pragma unroll
    for (int mi = 0; mi < 4; ++mi) af[mi] = *(const short8*)&As[wm * 64 + mi * 16 + lr][kq];
#pragma unroll
    for (int ni = 0; ni < 4; ++ni) bf[ni] = *(const short8*)&Bs[wn * 64 + ni * 16 + lr][kq];
#pragma unroll
    for (int mi = 0; mi < 4; ++mi)
#pragma unroll
      for (int ni = 0; ni < 4; ++ni)
        acc[mi][ni] = __builtin_amdgcn_mfma_f32_16x16x32_bf16(af[mi], bf[ni], acc[mi][ni], 0, 0, 0);
  }

#pragma unroll
  for (int mi = 0; mi < 4; ++mi)
#pragma unroll
    for (int ni = 0; ni < 4; ++ni)
#pragma unroll
      for (int rr = 0; rr < 4; ++rr)
        Cs[wm * 64 + mi * 16 + (lane >> 4) * 4 + rr][wn * 64 + ni * 16 + lr] =
            __float2bfloat16(acc[mi][ni][rr]);
  __syncthreads();

  const int orow = tid >> 1, oseg = (tid & 1) * 64;
  __hip_bfloat16* dst = xg + (size_t)(by * 128 + orow) * G4_ + bx * 128 + oseg;
#pragma unroll
  for (int c2 = 0; c2 < 8; ++c2)
    *(short8*)(dst + c2 * 8) = *(const short8*)&Cs[orow][oseg + c2 * 8];
}

// ---------------------------------------------------------------------------
// Persistent recurrent kernel (128 blocks x 256 thr, 4 waves, K-split 4x256).
// R6 structure; h broadcast now uses NORMAL cacheable loads + one agent-scope
// acquire fence per wave per step (emits buffer_inv sc1). First reader per
// XCD misses to the fresh LLC copy, the other ~15 blocks/XCD hit L2 ->
// ~16x less LLC broadcast traffic than sc0/sc1-bypass loads.
// Producer stores are agent-scope atomics (write-through to LLC, as before),
// drained before the flag post. Every h read is preceded by an inv in the
// same iteration, and flags>=t implies all blocks completed iteration t-1,
// so no stale-refill hazard across buffer parities.
// ---------------------------------------------------------------------------
__global__ __launch_bounds__(256, 1) void lstm_rec(
    const __hip_bfloat16* __restrict__ xg, const float* __restrict__ Whh,
    const int* __restrict__ lengths, const float* __restrict__ h0,
    const float* __restrict__ c0, const float* __restrict__ bih,
    const float* __restrict__ bhh, __hip_bfloat16* hbuf,
    float* __restrict__ hstate, float* __restrict__ cstate,
    int* flags, float* __restrict__ out,
    int t0, int t1, int isfirst, int islast) {
  __shared__ float Gs[4][32][36];   // stride 36 -> 2-way banks (free)

  const int g = blockIdx.x, tid = threadIdx.x;
  const int lane = tid & 63, w = tid >> 6;
  const int lr = lane & 15, q = lane >> 4, kq = q * 8;
  const int kkb = w * 8;                 // this wave's kk range: [kkb, kkb+8)

  // --- W_hh fragments -> registers (stationary) ---
  short8 wf[2][8];
#pragma unroll
  for (int ni = 0; ni < 2; ++ni) {
    const int n2 = ni * 16 + lr;
    const int gcol = (n2 >> 3) * H_ + g * JPB + (n2 & 7);
    const float* wbase = Whh + (size_t)gcol * H_ + kq;
#pragma unroll
    for (int kk2 = 0; kk2 < 8; ++kk2) {
      const int k0 = (kkb + kk2) * 32;
      f32x4 w0 = *(const f32x4*)(wbase + k0);
      f32x4 w1 = *(const f32x4*)(wbase + k0 + 4);
      __hip_bfloat16 tw_[8];
#pragma unroll
      for (int e = 0; e < 4; ++e) { tw_[e] = __float2bfloat16(w0[e]); tw_[4 + e] = __float2bfloat16(w1[e]); }
      wf[ni][kk2] = *(const short8*)&tw_[0];
    }
  }

  // nonlinearity ownership: threads 0..127, each owns (batch bb2, 2 cols)
  const int bb2 = (tid & 127) >> 2, j2 = (tid & 3) * 2;
  const int jglob = g * JPB + j2;
  const int len_b = (tid < 128) ? lengths[bb2] : 0;
  int maxlen = 0;
  for (int p = 0; p < B_; ++p) maxlen = max(maxlen, lengths[p]);
  const int tend = min(t1, maxlen);

  float hreg[2], creg[2], bias[4][2];
  if (tid < 128) {
    if (isfirst) {
#pragma unroll
      for (int e = 0; e < 2; ++e) { hreg[e] = h0[bb2 * H_ + jglob + e]; creg[e] = c0[bb2 * H_ + jglob + e]; }
    } else {
#pragma unroll
      for (int e = 0; e < 2; ++e) { hreg[e] = hstate[bb2 * H_ + jglob + e]; creg[e] = cstate[bb2 * H_ + jglob + e]; }
    }
#pragma unroll
    for (int p = 0; p < 4; ++p)
#pragma unroll
      for (int e = 0; e < 2; ++e)
        bias[p][e] = bih[p * H_ + jglob + e] + bhh[p * H_ + jglob + e];
  }

  unsigned long long* hbuf64 = (unsigned long long*)hbuf;
  const int* myflag = &flags[(w * 32 + (lane & 31)) * FSTRIDE];
  // producer u64 word index (even threads of each 4-group store cols pair+pair)
  const int pw64 = bb2 * (H_ / 4) + g * 2 + ((tid & 3) >> 1);

  for (int t = t0; t < tend; ++t) {
    // ---- xg loads: independent of h -> issue before the poll ----
    unsigned int xp[4];
    if (tid < 128) {
      const __hip_bfloat16* xgrow = xg + ((size_t)(t - t0) * B_ + bb2) * G4_ + jglob;
#pragma unroll
      for (int p = 0; p < 4; ++p) xp[p] = *(const unsigned int*)(xgrow + p * H_);
    }

    // ---- per-wave poll on padded flags ----
    while (true) {
      int f = __hip_atomic_load(myflag, __ATOMIC_RELAXED, __HIP_MEMORY_SCOPE_AGENT);
      if (__all(f >= t)) break;
      __builtin_amdgcn_s_sleep(1);
    }

    // ---- surgical acquire: invalidate stale L1/L2 ONCE, then cacheable loads
    //      -> 16 blocks/XCD share the fresh h lines through L2.
    __builtin_amdgcn_fence(__ATOMIC_ACQUIRE, "agent");

    const char* hb = (const char*)(hbuf + (size_t)(t & 1) * (B_ * H_));
    i32x4 raw[2][8];
#pragma unroll
    for (int mi = 0; mi < 2; ++mi) {
      const char* rowp = hb + (size_t)(mi * 16 + lr) * (H_ * 2) + kkb * 64 + q * 16;
#pragma unroll
      for (int kk2 = 0; kk2 < 8; ++kk2)
        raw[mi][kk2] = *(const i32x4*)(rowp + kk2 * 64);
    }

    short8 af[2][8];
#pragma unroll
    for (int mi = 0; mi < 2; ++mi)
#pragma unroll
      for (int kk2 = 0; kk2 < 8; ++kk2) {
        union { i32x4 i; short8 s; } cv;
        cv.i = raw[mi][kk2];
        af[mi][kk2] = cv.s;
      }

    // ---- MFMA: 32x32 tile over this wave's K=256 slice ----
    f32x4 acc[2][2];
#pragma unroll
    for (int mi = 0; mi < 2; ++mi)
#pragma unroll
      for (int ni = 0; ni < 2; ++ni) acc[mi][ni] = (f32x4){0.f, 0.f, 0.f, 0.f};
#pragma unroll
    for (int kk2 = 0; kk2 < 8; ++kk2)
#pragma unroll
      for (int mi = 0; mi < 2; ++mi)
#pragma unroll
        for (int ni = 0; ni < 2; ++ni)
          acc[mi][ni] = __builtin_amdgcn_mfma_f32_16x16x32_bf16(af[mi][kk2], wf[ni][kk2], acc[mi][ni], 0, 0, 0);

    // ---- write partials ----
#pragma unroll
    for (int mi = 0; mi < 2; ++mi)
#pragma unroll
      for (int ni = 0; ni < 2; ++ni)
#pragma unroll
        for (int rr = 0; rr < 4; ++rr)
          Gs[w][mi * 16 + q * 4 + rr][ni * 16 + lr] = acc[mi][ni][rr];
    __syncthreads();

    // ---- nonlinearity: thread (tid<128) owns (bb2, jglob..jglob+1) ----
    if (tid < 128) {
      const int upd = (t < len_b);
#pragma unroll
      for (int e = 0; e < 2; ++e) {
        const int cb = j2 + e;
        const float s0 = (Gs[0][bb2][cb]      + Gs[1][bb2][cb])      + (Gs[2][bb2][cb]      + Gs[3][bb2][cb]);
        const float s1 = (Gs[0][bb2][8 + cb]  + Gs[1][bb2][8 + cb])  + (Gs[2][bb2][8 + cb]  + Gs[3][bb2][8 + cb]);
        const float s2 = (Gs[0][bb2][16 + cb] + Gs[1][bb2][16 + cb]) + (Gs[2][bb2][16 + cb] + Gs[3][bb2][16 + cb]);
        const float s3 = (Gs[0][bb2][24 + cb] + Gs[1][bb2][24 + cb]) + (Gs[2][bb2][24 + cb] + Gs[3][bb2][24 + cb]);
        const float g0 = s0 + bf16bits_to_f((unsigned short)(xp[0] >> (16 * e))) + bias[0][e];
        const float g1 = s1 + bf16bits_to_f((unsigned short)(xp[1] >> (16 * e))) + bias[1][e];
        const float g2 = s2 + bf16bits_to_f((unsigned short)(xp[2] >> (16 * e))) + bias[2][e];
        const float g3 = s3 + bf16bits_to_f((unsigned short)(xp[3] >> (16 * e))) + bias[3][e];
        const float ig = sigmoidf_(g0), fg = sigmoidf_(g1);
        const float gg = tanhf_(g2),    og = sigmoidf_(g3);
        const float cn = fg * creg[e] + ig * gg;
        const float hn = og * tanhf_(cn);
        if (upd) { creg[e] = cn; hreg[e] = hn; }
      }
      unsigned int packed = ((unsigned int)f_to_bf16bits(hreg[1]) << 16) | f_to_bf16bits(hreg[0]);
      unsigned int other = __shfl_xor(packed, 1);   // partner holds cols +2
      if ((tid & 1) == 0) {
        unsigned long long w64 = ((unsigned long long)other << 32) | (unsigned long long)packed;
        __hip_atomic_store(hbuf64 + (size_t)((t + 1) & 1) * (B_ * H_ / 4) + pw64, w64,
                           __ATOMIC_RELAXED, __HIP_MEMORY_SCOPE_AGENT);
      }
    }
    __syncthreads();   // drains vmcnt -> h stores at LLC before flag
    if (tid == 0)
      __hip_atomic_store(&flags[g * FSTRIDE], t + 1, __ATOMIC_RELAXED, __HIP_MEMORY_SCOPE_AGENT);
  }

  if (tid < 128) {
    if (islast) {
#pragma unroll
      for (int e = 0; e < 2; ++e) {
        out[bb2 * H_ + jglob + e] = hreg[e];
        out[B_ * H_ + bb2 * H_ + jglob + e] = creg[e];
      }
    } else {
#pragma unroll
      for (int e = 0; e < 2; ++e) {
        hstate[bb2 * H_ + jglob + e] = hreg[e];
        cstate[bb2 * H_ + jglob + e] = creg[e];
      }
    }
  }
}

// init: h0 -> hbuf[0] (bf16), zero flags. Re-runs every launch (graph replay safe).
__global__ void init_k(const float* __restrict__ h0, __hip_bfloat16* __restrict__ hbuf,
                       int* __restrict__ flags) {
  int i = blockIdx.x * 256 + threadIdx.x;
  if (i < B_ * H_) hbuf[i] = __float2bfloat16(h0[i]);
  if (i < NBLK * FSTRIDE) flags[i] = 0;
}

extern "C" void kernel_launch(void* const* d_in, const int* in_sizes, int n_in,
                              void* d_out, int out_size, void* d_ws, size_t ws_size,
                              hipStream_t stream) {
  const float* x       = (const float*)d_in[0];
  const int*   lengths = (const int*)d_in[1];
  const float* h0      = (const float*)d_in[2];
  const float* c0      = (const float*)d_in[3];
  const float* Wih     = (const float*)d_in[4];
  const float* Whh     = (const float*)d_in[5];
  const float* bih     = (const float*)d_in[6];
  const float* bhh     = (const float*)d_in[7];
  float* out = (float*)d_out;

  char* ws = (char*)d_ws;
  int* flags               = (int*)ws;                               // 8 KB (padded)
  __hip_bfloat16* hbuf     = (__hip_bfloat16*)(ws + 8192);           // 2 x 64 KB
  float* hstate            = (float*)(ws + 8192 + 131072);           // 128 KB
  float* cstate            = (float*)(ws + 8192 + 262144);           // 128 KB
  __hip_bfloat16* xg       = (__hip_bfloat16*)(ws + 524288);

  size_t avail = (ws_size > 524288) ? ws_size - 524288 : 0;
  int tc = (int)(avail / ((size_t)B_ * G4_ * 2));
  if (tc > T_) tc = T_;
  tc &= ~3;               // M tile needs tc multiple of 4
  if (tc < 4) tc = 4;     // minimal chunk (assumes ws_size >= ~1.6 MB)

  hipLaunchKernelGGL(init_k, dim3(128), dim3(256), 0, stream, h0, hbuf, flags);
  for (int t0 = 0; t0 < T_; t0 += tc) {
    int len = min(tc, T_ - t0);
    dim3 gg(G4_ / 128, (len * B_) / 128);
    hipLaunchKernelGGL(xw_gemm, gg, dim3(256), 0, stream, x, Wih, xg, t0);
    hipLaunchKernelGGL(lstm_rec, dim3(NBLK), dim3(256), 0, stream,
                       xg, Whh, lengths, h0, c0, bih, bhh, hbuf, hstate, cstate,
                       flags, out, t0, t0 + len, (t0 == 0) ? 1 : 0,
                       (t0 + len >= T_) ? 1 : 0);
  }
}

// Round 8
// 12348.059 us; speedup vs baseline: 1.2568x; 1.2568x over previous
//
#include <hip/hip_runtime.h>
#include <hip/hip_bf16.h>

#define B_ 32
#define T_ 2048
#define D_ 512
#define H_ 1024
#define G4_ 4096
#define NBLK 64    // recurrent blocks (1 block/CU, co-resident)
#define JPB 16     // h-columns per recurrent block (H_/NBLK)

typedef __attribute__((ext_vector_type(8))) short short8;
typedef __attribute__((ext_vector_type(4))) float f32x4;
typedef __attribute__((ext_vector_type(4))) int i32x4;

__device__ __forceinline__ float sigmoidf_(float x) { return 1.0f / (1.0f + __expf(-x)); }
__device__ __forceinline__ float tanhf_(float x) {
  float e = __expf(2.0f * x);
  return 1.0f - 2.0f / (e + 1.0f);
}
__device__ __forceinline__ float bf16bits_to_f(unsigned short u) {
  return __builtin_bit_cast(float, (unsigned int)u << 16);
}
__device__ __forceinline__ unsigned short f_to_bf16bits(float f) {
  __hip_bfloat16 h = __float2bfloat16(f);
  return __builtin_bit_cast(unsigned short, h);
}

// 16B load bypassing L1/L2 (sc0 sc1): fresh from memory-side LLC, coalesces.
__device__ __forceinline__ i32x4 load16_sys(const void* p) {
  i32x4 v;
  asm volatile("global_load_dwordx4 %0, %1, off sc0 sc1" : "=v"(v) : "v"(p));
  return v;
}
// 16B store written through to LLC (sc0 sc1); drained by explicit vmcnt(0).
__device__ __forceinline__ void store16_sys(void* p, i32x4 v) {
  asm volatile("global_store_dwordx4 %0, %1, off sc0 sc1" :: "v"(p), "v"(v) : "memory");
}

// ---------------------------------------------------------------------------
// Precompute xg[row][col] = sum_k x[row][k] * W_ih[col][k]   (row = tloc*32+b)
// ---------------------------------------------------------------------------
__global__ __launch_bounds__(256) void xw_gemm(const float* __restrict__ x,
                                               const float* __restrict__ Wih,
                                               __hip_bfloat16* __restrict__ xg,
                                               int t0) {
  __shared__ __align__(16) __hip_bfloat16 As[128][40];
  __shared__ __align__(16) __hip_bfloat16 Bs[128][40];
  __shared__ __align__(16) __hip_bfloat16 Cs[128][132];

  const int tid = threadIdx.x;
  const int bx = blockIdx.x;           // N tile (0..31)
  const int by = blockIdx.y;           // M tile
  const int lane = tid & 63, wave = tid >> 6;
  const int wm = wave >> 1, wn = wave & 1;
  const int lr = lane & 15, kq = (lane >> 4) * 8;

  const int r  = tid >> 1, ks = (tid & 1) * 16;
  const int rowA = by * 128 + r;
  const int bb = rowA & 31, tg = t0 + (rowA >> 5);
  const float* aptr = x  + ((size_t)bb * T_ + tg) * D_ + ks;
  const float* bptr = Wih + (size_t)(bx * 128 + r) * D_ + ks;

  f32x4 acc[4][4];
#pragma unroll
  for (int i = 0; i < 4; ++i)
#pragma unroll
    for (int jj = 0; jj < 4; ++jj) acc[i][jj] = (f32x4){0.f, 0.f, 0.f, 0.f};

  for (int k0 = 0; k0 < D_; k0 += 32) {
    __hip_bfloat16 ta[16], tb[16];
#pragma unroll
    for (int q = 0; q < 4; ++q) {
      f32x4 va = ((const f32x4*)(aptr + k0))[q];
      f32x4 vb = ((const f32x4*)(bptr + k0))[q];
#pragma unroll
      for (int e = 0; e < 4; ++e) {
        ta[q * 4 + e] = __float2bfloat16(va[e]);
        tb[q * 4 + e] = __float2bfloat16(vb[e]);
      }
    }
    __syncthreads();  // protect previous iter's readers
    *(short8*)&As[r][ks]     = *(const short8*)&ta[0];
    *(short8*)&As[r][ks + 8] = *(const short8*)&ta[8];
    *(short8*)&Bs[r][ks]     = *(const short8*)&tb[0];
    *(short8*)&Bs[r][ks + 8] = *(const short8*)&tb[8];
    __syncthreads();

    short8 af[4], bf[4];
#pragma unroll
    for (int mi = 0; mi < 4; ++mi) af[mi] = *(const short8*)&As[wm * 64 + mi * 16 + lr][kq];
#pragma unroll
    for (int ni = 0; ni < 4; ++ni) bf[ni] = *(const short8*)&Bs[wn * 64 + ni * 16 + lr][kq];
#pragma unroll
    for (int mi = 0; mi < 4; ++mi)
#pragma unroll
      for (int ni = 0; ni < 4; ++ni)
        acc[mi][ni] = __builtin_amdgcn_mfma_f32_16x16x32_bf16(af[mi], bf[ni], acc[mi][ni], 0, 0, 0);
  }

#pragma unroll
  for (int mi = 0; mi < 4; ++mi)
#pragma unroll
    for (int ni = 0; ni < 4; ++ni)
#pragma unroll
      for (int rr = 0; rr < 4; ++rr)
        Cs[wm * 64 + mi * 16 + (lane >> 4) * 4 + rr][wn * 64 + ni * 16 + lr] =
            __float2bfloat16(acc[mi][ni][rr]);
  __syncthreads();

  const int orow = tid >> 1, oseg = (tid & 1) * 64;
  __hip_bfloat16* dst = xg + (size_t)(by * 128 + orow) * G4_ + bx * 128 + oseg;
#pragma unroll
  for (int c2 = 0; c2 < 8; ++c2)
    *(short8*)(dst + c2 * 8) = *(const short8*)&Cs[orow][oseg + c2 * 8];
}

// ---------------------------------------------------------------------------
// Persistent recurrent kernel: 64 blocks x 512 thr (8 waves = 8 K-slices).
// Block g owns h-cols [g*16, g*16+16) (=> 64 gate cols). Wave w computes the
// full 32x64 gate tile over K in [w*128, (w+1)*128), reading h DIRECTLY via
// coalescing sc0/sc1 dwordx4 loads (each h line read ONCE per block).
// Flags unpadded: wave w polls its 8 contiguous producers with one coalesced
// same-line load. Producer h-store: shfl-packed dwordx4 sc0/sc1 (coalesced),
// explicit vmcnt(0) drain, block barrier, then tid0 posts the flag.
// Safety (inductive, as R3/R6): a block overwrites hbuf[(t+1)&1] only after
// poll(t) saw ALL flags >= t, i.e. every block finished its step t-1 reads
// of that same parity; flag t+1 posted only after all waves' step-t reads
// (joined at the Gs barrier).
// ---------------------------------------------------------------------------
__global__ __launch_bounds__(512, 1) void lstm_rec(
    const __hip_bfloat16* __restrict__ xg, const float* __restrict__ Whh,
    const int* __restrict__ lengths, const float* __restrict__ h0,
    const float* __restrict__ c0, const float* __restrict__ bih,
    const float* __restrict__ bhh, __hip_bfloat16* hbuf,
    float* __restrict__ hstate, float* __restrict__ cstate,
    int* flags, float* __restrict__ out,
    int t0, int t1, int isfirst, int islast) {
  __shared__ float Gs[8][33][70];   // [k-slice][batch(+pad)][gate col(+pad)]

  const int g = blockIdx.x, tid = threadIdx.x;
  const int lane = tid & 63, w = tid >> 6;
  const int lr = lane & 15, q = lane >> 4, kq = q * 8;
  const int kkb = w * 4;                 // kk range [kkb, kkb+4), k = kk*32+kq+e

  // --- W_hh fragments -> registers (stationary). wf[ni][kk2]:
  // block-local gate col n = ni*16+lr in [0,64); global col = (n>>4)*H + g*16 + (n&15)
  short8 wf[4][4];
#pragma unroll
  for (int ni = 0; ni < 4; ++ni) {
    const int n = ni * 16 + lr;
    const int gcol = (n >> 4) * H_ + g * JPB + (n & 15);
    const float* wbase = Whh + (size_t)gcol * H_ + kq;
#pragma unroll
    for (int kk2 = 0; kk2 < 4; ++kk2) {
      const int k0 = (kkb + kk2) * 32;
      f32x4 w0 = *(const f32x4*)(wbase + k0);
      f32x4 w1 = *(const f32x4*)(wbase + k0 + 4);
      __hip_bfloat16 tw_[8];
#pragma unroll
      for (int e = 0; e < 4; ++e) { tw_[e] = __float2bfloat16(w0[e]); tw_[4 + e] = __float2bfloat16(w1[e]); }
      wf[ni][kk2] = *(const short8*)&tw_[0];
    }
  }

  // nonlinearity ownership: 512 threads, each owns (batch bb2, ONE col j1)
  const int bb2 = tid >> 4, j1 = tid & 15;
  const int jglob = g * JPB + j1;
  const int len_b = lengths[bb2];
  int maxlen = 0;
  for (int p = 0; p < B_; ++p) maxlen = max(maxlen, lengths[p]);
  const int tend = min(t1, maxlen);

  float hreg, creg, bias[4];
  if (isfirst) { hreg = h0[bb2 * H_ + jglob]; creg = c0[bb2 * H_ + jglob]; }
  else         { hreg = hstate[bb2 * H_ + jglob]; creg = cstate[bb2 * H_ + jglob]; }
#pragma unroll
  for (int p = 0; p < 4; ++p) bias[p] = bih[p * H_ + jglob] + bhh[p * H_ + jglob];

  // poll address: wave w's 8 producers = flags[w*8 .. w*8+8) (one 64B line pair)
  const int* myflag = &flags[w * 8 + (lane & 7)];
  // producer store: lane tid&7==0 of each 8-group stores 16B (8 cols) at
  // byte offset b*2048 + g*32 + half*16
  char* const hstore_base = (char*)hbuf;
  const size_t poff = (size_t)bb2 * (H_ * 2) + g * (JPB * 2) + ((tid >> 3) & 1) * 16;

  for (int t = t0; t < tend; ++t) {
    // ---- xg loads: independent of h -> issue before the poll ----
    float xv[4];
    {
      const __hip_bfloat16* xgrow = xg + ((size_t)(t - t0) * B_ + bb2) * G4_ + jglob;
#pragma unroll
      for (int p = 0; p < 4; ++p) xv[p] = __bfloat162float(xgrow[p * H_]);
    }

    // ---- per-wave poll: one coalesced line read of 8 producer flags ----
    while (true) {
      int f = __hip_atomic_load(myflag, __ATOMIC_RELAXED, __HIP_MEMORY_SCOPE_AGENT);
      if (__all((lane >= 8) || (f >= t))) break;
      __builtin_amdgcn_s_sleep(1);
    }

    // ---- A-fragments: coalescing 16B L2-bypass loads (each line once/block)
    const char* hb = (const char*)(hbuf + (size_t)(t & 1) * (B_ * H_));
    i32x4 raw[2][4];
#pragma unroll
    for (int mi = 0; mi < 2; ++mi) {
      const char* rowp = hb + (size_t)(mi * 16 + lr) * (H_ * 2) + kkb * 64 + q * 16;
#pragma unroll
      for (int kk2 = 0; kk2 < 4; ++kk2)
        raw[mi][kk2] = load16_sys(rowp + kk2 * 64);
    }
    asm volatile("s_waitcnt vmcnt(0)" ::: "memory");
    __builtin_amdgcn_sched_barrier(0);

    short8 af[2][4];
#pragma unroll
    for (int mi = 0; mi < 2; ++mi)
#pragma unroll
      for (int kk2 = 0; kk2 < 4; ++kk2) {
        union { i32x4 i; short8 s; } cv;
        cv.i = raw[mi][kk2];
        af[mi][kk2] = cv.s;
      }

    // ---- MFMA: 32x64 tile over this wave's K=128 slice ----
    f32x4 acc[2][4];
#pragma unroll
    for (int mi = 0; mi < 2; ++mi)
#pragma unroll
      for (int ni = 0; ni < 4; ++ni) acc[mi][ni] = (f32x4){0.f, 0.f, 0.f, 0.f};
#pragma unroll
    for (int kk2 = 0; kk2 < 4; ++kk2)
#pragma unroll
      for (int mi = 0; mi < 2; ++mi)
#pragma unroll
        for (int ni = 0; ni < 4; ++ni)
          acc[mi][ni] = __builtin_amdgcn_mfma_f32_16x16x32_bf16(af[mi][kk2], wf[ni][kk2], acc[mi][ni], 0, 0, 0);

    // ---- write partials ----
#pragma unroll
    for (int mi = 0; mi < 2; ++mi)
#pragma unroll
      for (int ni = 0; ni < 4; ++ni)
#pragma unroll
        for (int rr = 0; rr < 4; ++rr)
          Gs[w][mi * 16 + q * 4 + rr][ni * 16 + lr] = acc[mi][ni][rr];
    __syncthreads();

    // ---- nonlinearity: thread owns (bb2, j1) ----
    {
      const int upd = (t < len_b);
      float s[4];
#pragma unroll
      for (int p = 0; p < 4; ++p) {
        const int cb = p * 16 + j1;
        s[p] = ((Gs[0][bb2][cb] + Gs[1][bb2][cb]) + (Gs[2][bb2][cb] + Gs[3][bb2][cb])) +
               ((Gs[4][bb2][cb] + Gs[5][bb2][cb]) + (Gs[6][bb2][cb] + Gs[7][bb2][cb]));
      }
      const float ig = sigmoidf_(s[0] + xv[0] + bias[0]);
      const float fg = sigmoidf_(s[1] + xv[1] + bias[1]);
      const float gg = tanhf_(s[2] + xv[2] + bias[2]);
      const float og = sigmoidf_(s[3] + xv[3] + bias[3]);
      const float cn = fg * creg + ig * gg;
      const float hn = og * tanhf_(cn);
      if (upd) { creg = cn; hreg = hn; }

      // pack 8 cols (8 threads) -> one dwordx4 store in lane tid&7==0
      unsigned int hb16 = (unsigned int)f_to_bf16bits(hreg);
      unsigned int a01 = (hb16 & 0xFFFFu) | (__shfl_xor(hb16, 1) << 16);
      unsigned int a23 = __shfl_xor(a01, 2);
      unsigned int a45 = __shfl_xor(a01, 4);
      unsigned int a67 = __shfl_xor(a23, 4);
      if ((tid & 7) == 0) {
        i32x4 v; v[0] = (int)a01; v[1] = (int)a23; v[2] = (int)a45; v[3] = (int)a67;
        store16_sys(hstore_base + (size_t)((t + 1) & 1) * (B_ * H_ * 2) + poff, v);
        asm volatile("s_waitcnt vmcnt(0)" ::: "memory");
      }
    }
    __syncthreads();   // all stores drained (explicit vmcnt above) before flag
    if (tid == 0)
      __hip_atomic_store(&flags[g], t + 1, __ATOMIC_RELAXED, __HIP_MEMORY_SCOPE_AGENT);
  }

  if (islast) {
    out[bb2 * H_ + jglob] = hreg;
    out[B_ * H_ + bb2 * H_ + jglob] = creg;
  } else {
    hstate[bb2 * H_ + jglob] = hreg;
    cstate[bb2 * H_ + jglob] = creg;
  }
}

// init: h0 -> hbuf[0] (bf16), zero flags. Re-runs every launch (graph replay safe).
__global__ void init_k(const float* __restrict__ h0, __hip_bfloat16* __restrict__ hbuf,
                       int* __restrict__ flags) {
  int i = blockIdx.x * 256 + threadIdx.x;
  if (i < B_ * H_) hbuf[i] = __float2bfloat16(h0[i]);
  if (i < NBLK) flags[i] = 0;
}

extern "C" void kernel_launch(void* const* d_in, const int* in_sizes, int n_in,
                              void* d_out, int out_size, void* d_ws, size_t ws_size,
                              hipStream_t stream) {
  const float* x       = (const float*)d_in[0];
  const int*   lengths = (const int*)d_in[1];
  const float* h0      = (const float*)d_in[2];
  const float* c0      = (const float*)d_in[3];
  const float* Wih     = (const float*)d_in[4];
  const float* Whh     = (const float*)d_in[5];
  const float* bih     = (const float*)d_in[6];
  const float* bhh     = (const float*)d_in[7];
  float* out = (float*)d_out;

  char* ws = (char*)d_ws;
  int* flags               = (int*)ws;                               // 8 KB region
  __hip_bfloat16* hbuf     = (__hip_bfloat16*)(ws + 8192);           // 2 x 64 KB
  float* hstate            = (float*)(ws + 8192 + 131072);           // 128 KB
  float* cstate            = (float*)(ws + 8192 + 262144);           // 128 KB
  __hip_bfloat16* xg       = (__hip_bfloat16*)(ws + 524288);

  size_t avail = (ws_size > 524288) ? ws_size - 524288 : 0;
  int tc = (int)(avail / ((size_t)B_ * G4_ * 2));
  if (tc > T_) tc = T_;
  tc &= ~3;               // M tile needs tc multiple of 4
  if (tc < 4) tc = 4;     // minimal chunk (assumes ws_size >= ~1.6 MB)

  hipLaunchKernelGGL(init_k, dim3(128), dim3(256), 0, stream, h0, hbuf, flags);
  for (int t0 = 0; t0 < T_; t0 += tc) {
    int len = min(tc, T_ - t0);
    dim3 gg(G4_ / 128, (len * B_) / 128);
    hipLaunchKernelGGL(xw_gemm, gg, dim3(256), 0, stream, x, Wih, xg, t0);
    hipLaunchKernelGGL(lstm_rec, dim3(NBLK), dim3(512), 0, stream,
                       xg, Whh, lengths, h0, c0, bih, bhh, hbuf, hstate, cstate,
                       flags, out, t0, t0 + len, (t0 == 0) ? 1 : 0,
                       (t0 + len >= T_) ? 1 : 0);
  }
}

// Round 9
// 9255.581 us; speedup vs baseline: 1.6767x; 1.3341x over previous
//
#include <hip/hip_runtime.h>
#include <hip/hip_bf16.h>

#define B_ 32
#define T_ 2048
#define D_ 512
#define H_ 1024
#define G4_ 4096
#define NBLK 128   // 2 batch-groups x 64 col-groups; 1 block/CU, co-resident
#define CG_ 64     // col groups
#define JPB 16     // h-columns per col-group (H_/CG_)
#define MROW 16    // batch rows per batch-group

typedef __attribute__((ext_vector_type(8))) short short8;
typedef __attribute__((ext_vector_type(4))) float f32x4;
typedef __attribute__((ext_vector_type(4))) int i32x4;

__device__ __forceinline__ float sigmoidf_(float x) { return 1.0f / (1.0f + __expf(-x)); }
__device__ __forceinline__ float tanhf_(float x) {
  float e = __expf(2.0f * x);
  return 1.0f - 2.0f / (e + 1.0f);
}
__device__ __forceinline__ unsigned short f_to_bf16bits(float f) {
  __hip_bfloat16 h = __float2bfloat16(f);
  return __builtin_bit_cast(unsigned short, h);
}

// 16B load bypassing L1/L2 (sc0 sc1): fresh from memory-side LLC, coalesces.
__device__ __forceinline__ i32x4 load16_sys(const void* p) {
  i32x4 v;
  asm volatile("global_load_dwordx4 %0, %1, off sc0 sc1" : "=v"(v) : "v"(p));
  return v;
}
// 16B store written through to LLC (sc0 sc1); drained by explicit vmcnt(0).
__device__ __forceinline__ void store16_sys(void* p, i32x4 v) {
  asm volatile("global_store_dwordx4 %0, %1, off sc0 sc1" :: "v"(p), "v"(v) : "memory");
}

// ---------------------------------------------------------------------------
// Precompute xg[row][col] = sum_k x[row][k] * W_ih[col][k]   (row = tloc*32+b)
// ---------------------------------------------------------------------------
__global__ __launch_bounds__(256) void xw_gemm(const float* __restrict__ x,
                                               const float* __restrict__ Wih,
                                               __hip_bfloat16* __restrict__ xg,
                                               int t0) {
  __shared__ __align__(16) __hip_bfloat16 As[128][40];
  __shared__ __align__(16) __hip_bfloat16 Bs[128][40];
  __shared__ __align__(16) __hip_bfloat16 Cs[128][132];

  const int tid = threadIdx.x;
  const int bx = blockIdx.x;           // N tile (0..31)
  const int by = blockIdx.y;           // M tile
  const int lane = tid & 63, wave = tid >> 6;
  const int wm = wave >> 1, wn = wave & 1;
  const int lr = lane & 15, kq = (lane >> 4) * 8;

  const int r  = tid >> 1, ks = (tid & 1) * 16;
  const int rowA = by * 128 + r;
  const int bb = rowA & 31, tg = t0 + (rowA >> 5);
  const float* aptr = x  + ((size_t)bb * T_ + tg) * D_ + ks;
  const float* bptr = Wih + (size_t)(bx * 128 + r) * D_ + ks;

  f32x4 acc[4][4];
#pragma unroll
  for (int i = 0; i < 4; ++i)
#pragma unroll
    for (int jj = 0; jj < 4; ++jj) acc[i][jj] = (f32x4){0.f, 0.f, 0.f, 0.f};

  for (int k0 = 0; k0 < D_; k0 += 32) {
    __hip_bfloat16 ta[16], tb[16];
#pragma unroll
    for (int q = 0; q < 4; ++q) {
      f32x4 va = ((const f32x4*)(aptr + k0))[q];
      f32x4 vb = ((const f32x4*)(bptr + k0))[q];
#pragma unroll
      for (int e = 0; e < 4; ++e) {
        ta[q * 4 + e] = __float2bfloat16(va[e]);
        tb[q * 4 + e] = __float2bfloat16(vb[e]);
      }
    }
    __syncthreads();  // protect previous iter's readers
    *(short8*)&As[r][ks]     = *(const short8*)&ta[0];
    *(short8*)&As[r][ks + 8] = *(const short8*)&ta[8];
    *(short8*)&Bs[r][ks]     = *(const short8*)&tb[0];
    *(short8*)&Bs[r][ks + 8] = *(const short8*)&tb[8];
    __syncthreads();

    short8 af[4], bf[4];
#pragma unroll
    for (int mi = 0; mi < 4; ++mi) af[mi] = *(const short8*)&As[wm * 64 + mi * 16 + lr][kq];
#pragma unroll
    for (int ni = 0; ni < 4; ++ni) bf[ni] = *(const short8*)&Bs[wn * 64 + ni * 16 + lr][kq];
#pragma unroll
    for (int mi = 0; mi < 4; ++mi)
#pragma unroll
      for (int ni = 0; ni < 4; ++ni)
        acc[mi][ni] = __builtin_amdgcn_mfma_f32_16x16x32_bf16(af[mi], bf[ni], acc[mi][ni], 0, 0, 0);
  }

#pragma unroll
  for (int mi = 0; mi < 4; ++mi)
#pragma unroll
    for (int ni = 0; ni < 4; ++ni)
#pragma unroll
      for (int rr = 0; rr < 4; ++rr)
        Cs[wm * 64 + mi * 16 + (lane >> 4) * 4 + rr][wn * 64 + ni * 16 + lr] =
            __float2bfloat16(acc[mi][ni][rr]);
  __syncthreads();

  const int orow = tid >> 1, oseg = (tid & 1) * 64;
  __hip_bfloat16* dst = xg + (size_t)(by * 128 + orow) * G4_ + bx * 128 + oseg;
#pragma unroll
  for (int c2 = 0; c2 < 8; ++c2)
    *(short8*)(dst + c2 * 8) = *(const short8*)&Cs[orow][oseg + c2 * 8];
}

// ---------------------------------------------------------------------------
// Persistent recurrent kernel: 128 blocks x 256 thr (4 waves), BATCH-SPLIT.
// Block (bg = bid&1, cg = bid>>1): gates for batches [bg*16,bg*16+16) x
// h-cols [cg*16, cg*16+16) => M=16, N=64 gate cols, K=1024 (4 waves x 256).
// Each block reads only its 16 h rows (32KB) -> half of R6's broadcast, at
// R6's proven topology. The two bg groups are fully decoupled (separate flag
// ranges). Flags contiguous: wave w polls its 16 producers (bg,w*16..w*16+16)
// with one coalesced line read. Producer h-store: shfl-packed 16B sc0/sc1
// stores (2 per batch row per block), explicit vmcnt(0), barrier, flag.
// Safety (inductive, as R3/R6): a block overwrites hbuf[(t+1)&1] only after
// poll(t) saw its producers' flags >= t (they finished step t-1 reads of that
// parity); flag t+1 posted only after all waves' step-t reads (Gs barrier).
// ---------------------------------------------------------------------------
__global__ __launch_bounds__(256, 1) void lstm_rec(
    const __hip_bfloat16* __restrict__ xg, const float* __restrict__ Whh,
    const int* __restrict__ lengths, const float* __restrict__ h0,
    const float* __restrict__ c0, const float* __restrict__ bih,
    const float* __restrict__ bhh, __hip_bfloat16* hbuf,
    float* __restrict__ hstate, float* __restrict__ cstate,
    int* flags, float* __restrict__ out,
    int t0, int t1, int isfirst, int islast) {
  __shared__ float Gs[4][MROW][68];   // [k-slice][batch row][gate col]

  const int bid = blockIdx.x, tid = threadIdx.x;
  const int bg = bid & 1, cg = bid >> 1;
  const int lane = tid & 63, w = tid >> 6;
  const int lr = lane & 15, q = lane >> 4, kq = q * 8;
  const int kkb = w * 8;                 // kk range [kkb,kkb+8), k = kk*32+kq+e

  // --- W_hh fragments -> registers (stationary). wf[ni][kk2]:
  // gate ni, h-col cg*16+lr; k = (kkb+kk2)*32 + kq + e
  short8 wf[4][8];
#pragma unroll
  for (int ni = 0; ni < 4; ++ni) {
    const int gcol = ni * H_ + cg * JPB + lr;
    const float* wbase = Whh + (size_t)gcol * H_ + kq;
#pragma unroll
    for (int kk2 = 0; kk2 < 8; ++kk2) {
      const int k0 = (kkb + kk2) * 32;
      f32x4 w0 = *(const f32x4*)(wbase + k0);
      f32x4 w1 = *(const f32x4*)(wbase + k0 + 4);
      __hip_bfloat16 tw_[8];
#pragma unroll
      for (int e = 0; e < 4; ++e) { tw_[e] = __float2bfloat16(w0[e]); tw_[4 + e] = __float2bfloat16(w1[e]); }
      wf[ni][kk2] = *(const short8*)&tw_[0];
    }
  }

  // nonlinearity ownership: ALL 256 threads, each owns (batch row bloc, col j1)
  const int bloc = tid >> 4, j1 = tid & 15;
  const int b = bg * MROW + bloc;
  const int jglob = cg * JPB + j1;
  const int len_b = lengths[b];
  int maxlen = 0;
  for (int p = 0; p < B_; ++p) maxlen = max(maxlen, lengths[p]);
  const int tend = min(t1, maxlen);

  float hreg, creg, bias[4];
  if (isfirst) { hreg = h0[b * H_ + jglob]; creg = c0[b * H_ + jglob]; }
  else         { hreg = hstate[b * H_ + jglob]; creg = cstate[b * H_ + jglob]; }
#pragma unroll
  for (int p = 0; p < 4; ++p) bias[p] = bih[p * H_ + jglob] + bhh[p * H_ + jglob];

  // wave w's producers: blocks (bg, cgp) for cgp in [w*16, w*16+16)
  const int* myflag = &flags[bg * CG_ + w * 16 + lr];
  // producer store: lanes tid%8==0 store 16B; 2 stores per batch row
  char* const hstore_base = (char*)hbuf;
  const size_t poff = (size_t)b * (H_ * 2) + cg * (JPB * 2) + ((tid >> 3) & 1) * 16;

  for (int t = t0; t < tend; ++t) {
    // ---- xg loads: independent of h -> issue before the poll ----
    float xv[4];
    {
      const __hip_bfloat16* xgrow = xg + ((size_t)(t - t0) * B_ + b) * G4_ + jglob;
#pragma unroll
      for (int p = 0; p < 4; ++p) xv[p] = __bfloat162float(xgrow[p * H_]);
    }

    // ---- per-wave poll: one coalesced line read of 16 producer flags ----
    while (true) {
      int f = __hip_atomic_load(myflag, __ATOMIC_RELAXED, __HIP_MEMORY_SCOPE_AGENT);
      if (__all((lane >= 16) || (f >= t))) break;
      __builtin_amdgcn_s_sleep(1);
    }

    // ---- A-fragments: coalescing 16B L2-bypass loads (16 rows only) ----
    const char* hb = (const char*)(hbuf + (size_t)(t & 1) * (B_ * H_));
    const char* rowp = hb + (size_t)(bg * MROW + lr) * (H_ * 2) + kkb * 64 + q * 16;
    i32x4 raw[8];
#pragma unroll
    for (int kk2 = 0; kk2 < 8; ++kk2)
      raw[kk2] = load16_sys(rowp + kk2 * 64);
    asm volatile("s_waitcnt vmcnt(0)" ::: "memory");
    __builtin_amdgcn_sched_barrier(0);

    short8 af[8];
#pragma unroll
    for (int kk2 = 0; kk2 < 8; ++kk2) {
      union { i32x4 i; short8 s; } cv;
      cv.i = raw[kk2];
      af[kk2] = cv.s;
    }

    // ---- MFMA: 16x64 tile over this wave's K=256 slice ----
    f32x4 acc[4];
#pragma unroll
    for (int ni = 0; ni < 4; ++ni) acc[ni] = (f32x4){0.f, 0.f, 0.f, 0.f};
#pragma unroll
    for (int kk2 = 0; kk2 < 8; ++kk2)
#pragma unroll
      for (int ni = 0; ni < 4; ++ni)
        acc[ni] = __builtin_amdgcn_mfma_f32_16x16x32_bf16(af[kk2], wf[ni][kk2], acc[ni], 0, 0, 0);

    // ---- write partials ----
#pragma unroll
    for (int ni = 0; ni < 4; ++ni)
#pragma unroll
      for (int rr = 0; rr < 4; ++rr)
        Gs[w][q * 4 + rr][ni * 16 + lr] = acc[ni][rr];
    __syncthreads();

    // ---- nonlinearity: thread owns (b, jglob); 16 LDS reads ----
    {
      const int upd = (t < len_b);
      float s[4];
#pragma unroll
      for (int p = 0; p < 4; ++p) {
        const int cb = p * 16 + j1;
        s[p] = (Gs[0][bloc][cb] + Gs[1][bloc][cb]) + (Gs[2][bloc][cb] + Gs[3][bloc][cb]);
      }
      const float ig = sigmoidf_(s[0] + xv[0] + bias[0]);
      const float fg = sigmoidf_(s[1] + xv[1] + bias[1]);
      const float gg = tanhf_(s[2] + xv[2] + bias[2]);
      const float og = sigmoidf_(s[3] + xv[3] + bias[3]);
      const float cn = fg * creg + ig * gg;
      const float hn = og * tanhf_(cn);
      if (upd) { creg = cn; hreg = hn; }

      // pack 8 cols (8 threads) -> one dwordx4 store in lane tid%8==0
      unsigned int hb16 = (unsigned int)f_to_bf16bits(hreg);
      unsigned int a01 = (hb16 & 0xFFFFu) | (__shfl_xor(hb16, 1) << 16);
      unsigned int a23 = __shfl_xor(a01, 2);
      unsigned int a45 = __shfl_xor(a01, 4);
      unsigned int a67 = __shfl_xor(a23, 4);
      if ((tid & 7) == 0) {
        i32x4 v; v[0] = (int)a01; v[1] = (int)a23; v[2] = (int)a45; v[3] = (int)a67;
        store16_sys(hstore_base + (size_t)((t + 1) & 1) * (B_ * H_ * 2) + poff, v);
      }
      asm volatile("s_waitcnt vmcnt(0)" ::: "memory");
    }
    __syncthreads();   // all stores drained (explicit vmcnt above) before flag
    if (tid == 0)
      __hip_atomic_store(&flags[bg * CG_ + cg], t + 1, __ATOMIC_RELAXED, __HIP_MEMORY_SCOPE_AGENT);
  }

  if (islast) {
    out[b * H_ + jglob] = hreg;
    out[B_ * H_ + b * H_ + jglob] = creg;
  } else {
    hstate[b * H_ + jglob] = hreg;
    cstate[b * H_ + jglob] = creg;
  }
}

// init: h0 -> hbuf[0] (bf16), zero flags. Re-runs every launch (graph replay safe).
__global__ void init_k(const float* __restrict__ h0, __hip_bfloat16* __restrict__ hbuf,
                       int* __restrict__ flags) {
  int i = blockIdx.x * 256 + threadIdx.x;
  if (i < B_ * H_) hbuf[i] = __float2bfloat16(h0[i]);
  if (i < NBLK) flags[i] = 0;
}

extern "C" void kernel_launch(void* const* d_in, const int* in_sizes, int n_in,
                              void* d_out, int out_size, void* d_ws, size_t ws_size,
                              hipStream_t stream) {
  const float* x       = (const float*)d_in[0];
  const int*   lengths = (const int*)d_in[1];
  const float* h0      = (const float*)d_in[2];
  const float* c0      = (const float*)d_in[3];
  const float* Wih     = (const float*)d_in[4];
  const float* Whh     = (const float*)d_in[5];
  const float* bih     = (const float*)d_in[6];
  const float* bhh     = (const float*)d_in[7];
  float* out = (float*)d_out;

  char* ws = (char*)d_ws;
  int* flags               = (int*)ws;                               // 8 KB region
  __hip_bfloat16* hbuf     = (__hip_bfloat16*)(ws + 8192);           // 2 x 64 KB
  float* hstate            = (float*)(ws + 8192 + 131072);           // 128 KB
  float* cstate            = (float*)(ws + 8192 + 262144);           // 128 KB
  __hip_bfloat16* xg       = (__hip_bfloat16*)(ws + 524288);

  size_t avail = (ws_size > 524288) ? ws_size - 524288 : 0;
  int tc = (int)(avail / ((size_t)B_ * G4_ * 2));
  if (tc > T_) tc = T_;
  tc &= ~3;               // M tile needs tc multiple of 4
  if (tc < 4) tc = 4;     // minimal chunk (assumes ws_size >= ~1.6 MB)

  hipLaunchKernelGGL(init_k, dim3(128), dim3(256), 0, stream, h0, hbuf, flags);
  for (int t0 = 0; t0 < T_; t0 += tc) {
    int len = min(tc, T_ - t0);
    dim3 gg(G4_ / 128, (len * B_) / 128);
    hipLaunchKernelGGL(xw_gemm, gg, dim3(256), 0, stream, x, Wih, xg, t0);
    hipLaunchKernelGGL(lstm_rec, dim3(NBLK), dim3(256), 0, stream,
                       xg, Whh, lengths, h0, c0, bih, bhh, hbuf, hstate, cstate,
                       flags, out, t0, t0 + len, (t0 == 0) ? 1 : 0,
                       (t0 + len >= T_) ? 1 : 0);
  }
}

// Round 12
// 9243.626 us; speedup vs baseline: 1.6788x; 1.0013x over previous
//
#include <hip/hip_runtime.h>
#include <hip/hip_bf16.h>

#define B_ 32
#define T_ 2048
#define D_ 512
#define H_ 1024
#define G4_ 4096
#define NBLK 128   // 2 batch-groups x 64 col-groups; 1 block/CU, co-resident
#define CG_ 64     // col groups
#define JPB 16     // h-columns per col-group (H_/CG_)
#define MROW 16    // batch rows per batch-group

typedef __attribute__((ext_vector_type(8))) short short8;
typedef __attribute__((ext_vector_type(4))) float f32x4;
typedef __attribute__((ext_vector_type(4))) int i32x4;

__device__ __forceinline__ float sigmoidf_(float x) { return 1.0f / (1.0f + __expf(-x)); }
__device__ __forceinline__ float tanhf_(float x) {
  float e = __expf(2.0f * x);
  return 1.0f - 2.0f / (e + 1.0f);
}
__device__ __forceinline__ unsigned short f_to_bf16bits(float f) {
  __hip_bfloat16 h = __float2bfloat16(f);
  return __builtin_bit_cast(unsigned short, h);
}

// 16B load bypassing L1/L2 (sc0 sc1): fresh from memory-side LLC, coalesces.
__device__ __forceinline__ i32x4 load16_sys(const void* p) {
  i32x4 v;
  asm volatile("global_load_dwordx4 %0, %1, off sc0 sc1" : "=v"(v) : "v"(p));
  return v;
}
// 4B LLC-fresh load (sc0 sc1), value ready on return (vmcnt inside). Coalesces
// across lanes (unlike atomic loads) -> 1 line op per wave poll retry.
__device__ __forceinline__ int load4_sys(const int* p) {
  int v;
  asm volatile("global_load_dword %0, %1, off sc0 sc1\n\t"
               "s_waitcnt vmcnt(0)"
               : "=v"(v) : "v"(p) : "memory");
  return v;
}
// 16B store written through to LLC (sc0 sc1); drained by explicit vmcnt(0).
__device__ __forceinline__ void store16_sys(void* p, i32x4 v) {
  asm volatile("global_store_dwordx4 %0, %1, off sc0 sc1" :: "v"(p), "v"(v) : "memory");
}

// ---------------------------------------------------------------------------
// Precompute xg[row][col] = sum_k x[row][k] * W_ih[col][k]   (row = tloc*32+b)
// ---------------------------------------------------------------------------
__global__ __launch_bounds__(256) void xw_gemm(const float* __restrict__ x,
                                               const float* __restrict__ Wih,
                                               __hip_bfloat16* __restrict__ xg,
                                               int t0) {
  __shared__ __align__(16) __hip_bfloat16 As[128][40];
  __shared__ __align__(16) __hip_bfloat16 Bs[128][40];
  __shared__ __align__(16) __hip_bfloat16 Cs[128][132];

  const int tid = threadIdx.x;
  const int bx = blockIdx.x;           // N tile (0..31)
  const int by = blockIdx.y;           // M tile
  const int lane = tid & 63, wave = tid >> 6;
  const int wm = wave >> 1, wn = wave & 1;
  const int lr = lane & 15, kq = (lane >> 4) * 8;

  const int r  = tid >> 1, ks = (tid & 1) * 16;
  const int rowA = by * 128 + r;
  const int bb = rowA & 31, tg = t0 + (rowA >> 5);
  const float* aptr = x  + ((size_t)bb * T_ + tg) * D_ + ks;
  const float* bptr = Wih + (size_t)(bx * 128 + r) * D_ + ks;

  f32x4 acc[4][4];
#pragma unroll
  for (int i = 0; i < 4; ++i)
#pragma unroll
    for (int jj = 0; jj < 4; ++jj) acc[i][jj] = (f32x4){0.f, 0.f, 0.f, 0.f};

  for (int k0 = 0; k0 < D_; k0 += 32) {
    __hip_bfloat16 ta[16], tb[16];
#pragma unroll
    for (int q = 0; q < 4; ++q) {
      f32x4 va = ((const f32x4*)(aptr + k0))[q];
      f32x4 vb = ((const f32x4*)(bptr + k0))[q];
#pragma unroll
      for (int e = 0; e < 4; ++e) {
        ta[q * 4 + e] = __float2bfloat16(va[e]);
        tb[q * 4 + e] = __float2bfloat16(vb[e]);
      }
    }
    __syncthreads();  // protect previous iter's readers
    *(short8*)&As[r][ks]     = *(const short8*)&ta[0];
    *(short8*)&As[r][ks + 8] = *(const short8*)&ta[8];
    *(short8*)&Bs[r][ks]     = *(const short8*)&tb[0];
    *(short8*)&Bs[r][ks + 8] = *(const short8*)&tb[8];
    __syncthreads();

    short8 af[4], bf[4];
#pragma unroll
    for (int mi = 0; mi < 4; ++mi) af[mi] = *(const short8*)&As[wm * 64 + mi * 16 + lr][kq];
#pragma unroll
    for (int ni = 0; ni < 4; ++ni) bf[ni] = *(const short8*)&Bs[wn * 64 + ni * 16 + lr][kq];
#pragma unroll
    for (int mi = 0; mi < 4; ++mi)
#pragma unroll
      for (int ni = 0; ni < 4; ++ni)
        acc[mi][ni] = __builtin_amdgcn_mfma_f32_16x16x32_bf16(af[mi], bf[ni], acc[mi][ni], 0, 0, 0);
  }

#pragma unroll
  for (int mi = 0; mi < 4; ++mi)
#pragma unroll
    for (int ni = 0; ni < 4; ++ni)
#pragma unroll
      for (int rr = 0; rr < 4; ++rr)
        Cs[wm * 64 + mi * 16 + (lane >> 4) * 4 + rr][wn * 64 + ni * 16 + lr] =
            __float2bfloat16(acc[mi][ni][rr]);
  __syncthreads();

  const int orow = tid >> 1, oseg = (tid & 1) * 64;
  __hip_bfloat16* dst = xg + (size_t)(by * 128 + orow) * G4_ + bx * 128 + oseg;
#pragma unroll
  for (int c2 = 0; c2 < 8; ++c2)
    *(short8*)(dst + c2 * 8) = *(const short8*)&Cs[orow][oseg + c2 * 8];
}

// ---------------------------------------------------------------------------
// Persistent recurrent kernel: 128 blocks x 256 thr (4 waves), batch-split
// (R9 structure, VERIFIED pre+post timing). Single change vs R9: the flag
// poll uses a coalescing sc0/sc1 plain load instead of per-lane atomic loads
// (16 LLC ops -> 1 per wave retry). Protocol identical: flags monotone; a
// plain load can only return an already-written (lower-or-equal) value, so
// the break condition f>=t still implies the producer posted after its data
// drain. Safety induction unchanged from R3/R6/R9.
// ---------------------------------------------------------------------------
__global__ __launch_bounds__(256, 1) void lstm_rec(
    const __hip_bfloat16* __restrict__ xg, const float* __restrict__ Whh,
    const int* __restrict__ lengths, const float* __restrict__ h0,
    const float* __restrict__ c0, const float* __restrict__ bih,
    const float* __restrict__ bhh, __hip_bfloat16* hbuf,
    float* __restrict__ hstate, float* __restrict__ cstate,
    int* flags, float* __restrict__ out,
    int t0, int t1, int isfirst, int islast) {
  __shared__ float Gs[4][MROW][68];   // [k-slice][batch row][gate col]

  const int bid = blockIdx.x, tid = threadIdx.x;
  const int bg = bid & 1, cg = bid >> 1;
  const int lane = tid & 63, w = tid >> 6;
  const int lr = lane & 15, q = lane >> 4, kq = q * 8;
  const int kkb = w * 8;                 // kk range [kkb,kkb+8), k = kk*32+kq+e

  // --- W_hh fragments -> registers (stationary). wf[ni][kk2]:
  // gate ni, h-col cg*16+lr; k = (kkb+kk2)*32 + kq + e
  short8 wf[4][8];
#pragma unroll
  for (int ni = 0; ni < 4; ++ni) {
    const int gcol = ni * H_ + cg * JPB + lr;
    const float* wbase = Whh + (size_t)gcol * H_ + kq;
#pragma unroll
    for (int kk2 = 0; kk2 < 8; ++kk2) {
      const int k0 = (kkb + kk2) * 32;
      f32x4 w0 = *(const f32x4*)(wbase + k0);
      f32x4 w1 = *(const f32x4*)(wbase + k0 + 4);
      __hip_bfloat16 tw_[8];
#pragma unroll
      for (int e = 0; e < 4; ++e) { tw_[e] = __float2bfloat16(w0[e]); tw_[4 + e] = __float2bfloat16(w1[e]); }
      wf[ni][kk2] = *(const short8*)&tw_[0];
    }
  }

  // nonlinearity ownership: ALL 256 threads, each owns (batch row bloc, col j1)
  const int bloc = tid >> 4, j1 = tid & 15;
  const int b = bg * MROW + bloc;
  const int jglob = cg * JPB + j1;
  const int len_b = lengths[b];
  int maxlen = 0;
  for (int p = 0; p < B_; ++p) maxlen = max(maxlen, lengths[p]);
  const int tend = min(t1, maxlen);

  float hreg, creg, bias[4];
  if (isfirst) { hreg = h0[b * H_ + jglob]; creg = c0[b * H_ + jglob]; }
  else         { hreg = hstate[b * H_ + jglob]; creg = cstate[b * H_ + jglob]; }
#pragma unroll
  for (int p = 0; p < 4; ++p) bias[p] = bih[p * H_ + jglob] + bhh[p * H_ + jglob];

  // wave w's producers: blocks (bg, cgp), cgp in [w*16, w*16+16)
  const int* myflag = &flags[bg * CG_ + w * 16 + lr];
  // producer store: lanes tid%8==0 store 16B; 2 stores per batch row
  char* const hstore_base = (char*)hbuf;
  const size_t poff = (size_t)b * (H_ * 2) + cg * (JPB * 2) + ((tid >> 3) & 1) * 16;

  for (int t = t0; t < tend; ++t) {
    // ---- xg loads: independent of h -> issue before the poll ----
    float xv[4];
    {
      const __hip_bfloat16* xgrow = xg + ((size_t)(t - t0) * B_ + b) * G4_ + jglob;
#pragma unroll
      for (int p = 0; p < 4; ++p) xv[p] = __bfloat162float(xgrow[p * H_]);
    }

    // ---- per-wave poll: ONE coalesced line read of 16 producer flags ----
    while (true) {
      int f = load4_sys(myflag);
      if (__all((lane >= 16) || (f >= t))) break;
      __builtin_amdgcn_s_sleep(1);
    }

    // ---- A-fragments: coalescing 16B L2-bypass loads (16 rows only) ----
    const char* hb = (const char*)(hbuf + (size_t)(t & 1) * (B_ * H_));
    const char* rowp = hb + (size_t)(bg * MROW + lr) * (H_ * 2) + kkb * 64 + q * 16;
    i32x4 raw[8];
#pragma unroll
    for (int kk2 = 0; kk2 < 8; ++kk2)
      raw[kk2] = load16_sys(rowp + kk2 * 64);
    asm volatile("s_waitcnt vmcnt(0)" ::: "memory");
    __builtin_amdgcn_sched_barrier(0);

    short8 af[8];
#pragma unroll
    for (int kk2 = 0; kk2 < 8; ++kk2) {
      union { i32x4 i; short8 s; } cv;
      cv.i = raw[kk2];
      af[kk2] = cv.s;
    }

    // ---- MFMA: 16x64 tile over this wave's K=256 slice ----
    f32x4 acc[4];
#pragma unroll
    for (int ni = 0; ni < 4; ++ni) acc[ni] = (f32x4){0.f, 0.f, 0.f, 0.f};
#pragma unroll
    for (int kk2 = 0; kk2 < 8; ++kk2)
#pragma unroll
      for (int ni = 0; ni < 4; ++ni)
        acc[ni] = __builtin_amdgcn_mfma_f32_16x16x32_bf16(af[kk2], wf[ni][kk2], acc[ni], 0, 0, 0);

    // ---- write partials ----
#pragma unroll
    for (int ni = 0; ni < 4; ++ni)
#pragma unroll
      for (int rr = 0; rr < 4; ++rr)
        Gs[w][q * 4 + rr][ni * 16 + lr] = acc[ni][rr];
    __syncthreads();

    // ---- nonlinearity: thread owns (b, jglob); 16 LDS reads ----
    {
      const int upd = (t < len_b);
      float s[4];
#pragma unroll
      for (int p = 0; p < 4; ++p) {
        const int cb = p * 16 + j1;
        s[p] = (Gs[0][bloc][cb] + Gs[1][bloc][cb]) + (Gs[2][bloc][cb] + Gs[3][bloc][cb]);
      }
      const float ig = sigmoidf_(s[0] + xv[0] + bias[0]);
      const float fg = sigmoidf_(s[1] + xv[1] + bias[1]);
      const float gg = tanhf_(s[2] + xv[2] + bias[2]);
      const float og = sigmoidf_(s[3] + xv[3] + bias[3]);
      const float cn = fg * creg + ig * gg;
      const float hn = og * tanhf_(cn);
      if (upd) { creg = cn; hreg = hn; }

      // pack 8 cols (8 threads) -> one dwordx4 store in lane tid%8==0
      unsigned int hb16 = (unsigned int)f_to_bf16bits(hreg);
      unsigned int a01 = (hb16 & 0xFFFFu) | (__shfl_xor(hb16, 1) << 16);
      unsigned int a23 = __shfl_xor(a01, 2);
      unsigned int a45 = __shfl_xor(a01, 4);
      unsigned int a67 = __shfl_xor(a23, 4);
      if ((tid & 7) == 0) {
        i32x4 v; v[0] = (int)a01; v[1] = (int)a23; v[2] = (int)a45; v[3] = (int)a67;
        store16_sys(hstore_base + (size_t)((t + 1) & 1) * (B_ * H_ * 2) + poff, v);
      }
      asm volatile("s_waitcnt vmcnt(0)" ::: "memory");
    }
    __syncthreads();   // all stores drained (explicit vmcnt above) before flag
    if (tid == 0)
      __hip_atomic_store(&flags[bg * CG_ + cg], t + 1, __ATOMIC_RELAXED, __HIP_MEMORY_SCOPE_AGENT);
  }

  if (islast) {
    out[b * H_ + jglob] = hreg;
    out[B_ * H_ + b * H_ + jglob] = creg;
  } else {
    hstate[b * H_ + jglob] = hreg;
    cstate[b * H_ + jglob] = creg;
  }
}

// init: h0 -> hbuf[0] (bf16), zero flags. Re-runs every launch (graph replay safe).
__global__ void init_k(const float* __restrict__ h0, __hip_bfloat16* __restrict__ hbuf,
                       int* __restrict__ flags) {
  int i = blockIdx.x * 256 + threadIdx.x;
  if (i < B_ * H_) hbuf[i] = __float2bfloat16(h0[i]);
  if (i < NBLK) flags[i] = 0;
}

extern "C" void kernel_launch(void* const* d_in, const int* in_sizes, int n_in,
                              void* d_out, int out_size, void* d_ws, size_t ws_size,
                              hipStream_t stream) {
  const float* x       = (const float*)d_in[0];
  const int*   lengths = (const int*)d_in[1];
  const float* h0      = (const float*)d_in[2];
  const float* c0      = (const float*)d_in[3];
  const float* Wih     = (const float*)d_in[4];
  const float* Whh     = (const float*)d_in[5];
  const float* bih     = (const float*)d_in[6];
  const float* bhh     = (const float*)d_in[7];
  float* out = (float*)d_out;

  char* ws = (char*)d_ws;
  int* flags               = (int*)ws;                               // 8 KB region
  __hip_bfloat16* hbuf     = (__hip_bfloat16*)(ws + 8192);           // 2 x 64 KB
  float* hstate            = (float*)(ws + 8192 + 131072);           // 128 KB
  float* cstate            = (float*)(ws + 8192 + 262144);           // 128 KB
  __hip_bfloat16* xg       = (__hip_bfloat16*)(ws + 524288);

  size_t avail = (ws_size > 524288) ? ws_size - 524288 : 0;
  int tc = (int)(avail / ((size_t)B_ * G4_ * 2));
  if (tc > T_) tc = T_;
  tc &= ~3;               // M tile needs tc multiple of 4
  if (tc < 4) tc = 4;     // minimal chunk (assumes ws_size >= ~1.6 MB)

  hipLaunchKernelGGL(init_k, dim3(128), dim3(256), 0, stream, h0, hbuf, flags);
  for (int t0 = 0; t0 < T_; t0 += tc) {
    int len = min(tc, T_ - t0);
    dim3 gg(G4_ / 128, (len * B_) / 128);
    hipLaunchKernelGGL(xw_gemm, gg, dim3(256), 0, stream, x, Wih, xg, t0);
    hipLaunchKernelGGL(lstm_rec, dim3(NBLK), dim3(256), 0, stream,
                       xg, Whh, lengths, h0, c0, bih, bhh, hbuf, hstate, cstate,
                       flags, out, t0, t0 + len, (t0 == 0) ? 1 : 0,
                       (t0 + len >= T_) ? 1 : 0);
  }
}